// Round 3
// baseline (1130.302 us; speedup 1.0000x reference)
//
#include <hip/hip_runtime.h>

#define TOK 16384
#define DD 1024
#define HH 2048
#define AA 128
#define EE 8
#define SS 2048
#define BB 8

typedef __attribute__((ext_vector_type(8))) short short8;
typedef __attribute__((ext_vector_type(4))) float floatx4;

__device__ __forceinline__ unsigned short f2b(float f) {
  unsigned u = __float_as_uint(f);
  u += 0x7fff + ((u >> 16) & 1);          // RNE
  return (unsigned short)(u >> 16);
}
__device__ __forceinline__ float b2f(unsigned short h) {
  return __uint_as_float(((unsigned)h) << 16);
}

__device__ __forceinline__ void xcd_swizzle(int& bx, int& by) {
  const int nbx = gridDim.x, nby = gridDim.y;
  if ((nby & 7) == 0) {
    const int L = blockIdx.y * nbx + blockIdx.x;
    const int xcd = L & 7, idx = L >> 3;
    bx = idx % nbx;
    by = (xcd * (nby >> 3)) + idx / nbx;
  } else {
    bx = blockIdx.x; by = blockIdx.y;
  }
}

// ================= 256x256 GEMM, 4-phase/tile ring with counted waits =================
// 512 thr = 8 waves (2M x 4N), BK=64, LDS 128KiB (2 bufs x (A 32K + B 32K)).
// Per tile t: ph0 rd afLow+afHigh(t), stage (t+1).Ah0 ; ph1 rd bfHigh(t), stage (t+1).Ah1,
// vmcnt(4) [(t+1).B landed] ; ph2 rd bfLow(t+1) ; ph3 stage (t+2).B, vmcnt(4) [(t+1).A landed].
// Every MFMA wait is a COUNTED lgkmcnt (8/4/4/4) — never a drain-0 in steady state.
// Ring verified (FIFO accounting incl. prologue + both tail tiles): loads drained by a
// fence are always >=2 phases old; buffers staged only after all cross-wave reads serviced
// (each read serviced by the NEXT phase's counted wait, ordered by that phase's end barrier).

__device__ __forceinline__ void gload16(const short* g, short* l) {
  __builtin_amdgcn_global_load_lds((__attribute__((address_space(1))) void*)(void*)g,
                                   (__attribute__((address_space(3))) void*)l, 16, 0, 0);
}

// full 256x64 tile = 4 x global_load_lds per thread; src pre-offset (+arow*ld + kc8)
__device__ __forceinline__ void stage_tile(const short* src, int ld, short* dst, int wave) {
#pragma unroll
  for (int i = 0; i < 4; ++i)
    gload16(src + (long)i*64*ld, dst + i*4096 + wave*512);
}

#define PHASE_MFMA(LG, M0, N0)                                                           \
  __builtin_amdgcn_s_barrier();                                                          \
  asm volatile("s_waitcnt lgkmcnt(" #LG ")" ::: "memory");                               \
  __builtin_amdgcn_sched_barrier(0);                                                     \
  __builtin_amdgcn_s_setprio(1);                                                         \
  _Pragma("unroll")                                                                      \
  for (int kk = 0; kk < 2; ++kk)                                                         \
    _Pragma("unroll")                                                                    \
    for (int m = 0; m < 4; ++m)                                                          \
      _Pragma("unroll")                                                                  \
      for (int n = 0; n < 2; ++n)                                                        \
        acc[M0+m][N0+n] = __builtin_amdgcn_mfma_f32_16x16x32_bf16(af[M0+m][kk], bf[N0+n][kk], acc[M0+m][N0+n], 0, 0, 0); \
  __builtin_amdgcn_s_setprio(0);                                                         \
  __builtin_amdgcn_s_barrier();

// Quadrants: Q0=(m0-3,n0-1) ph0, Q1=(m4-7,n0-1) ph1, Q2=(m0-3,n2-3) ph2, Q3=(m4-7,n2-3) ph3.
// Liveness (single-buffered frags): afLow(t) dead after ph2, afHigh dead after ph3,
// bfLow(t) dead after ph1 (t+1's read at ph2), bfHigh dead after ph3.
__device__ __forceinline__ void ktile8(const char* cA, const char* cB,   // current bufs
                                       const char* nB,                   // next B buf (bfLow(t+1) read)
                                       short* nAd, short* cBd,           // stage dests
                                       const short* sA1, int lA1,        // (t+1).A global src
                                       const short* sB2, int lB2,        // (t+2).B global src
                                       bool stA, bool stB, bool rd, int wave,
                                       int aOff, int bOff, int slot0, int slot1,
                                       short8 (&af)[8][2], short8 (&bf)[4][2],
                                       floatx4 (*acc)[4])
{
  // ---- ph0: rd afLow(t)[8 first] + afHigh(t)[8]; stage (t+1).Ah0 ----
#pragma unroll
  for (int m = 0; m < 4; ++m) {
    af[m][0] = *(const short8*)(cA + aOff + m*2048 + slot0);
    af[m][1] = *(const short8*)(cA + aOff + m*2048 + slot1);
  }
#pragma unroll
  for (int m = 4; m < 8; ++m) {
    af[m][0] = *(const short8*)(cA + aOff + m*2048 + slot0);
    af[m][1] = *(const short8*)(cA + aOff + m*2048 + slot1);
  }
  if (stA) {
    gload16(sA1 + 0L*64*lA1, nAd + 0*4096 + wave*512);
    gload16(sA1 + 1L*64*lA1, nAd + 1*4096 + wave*512);
  }
  PHASE_MFMA(8, 0, 0)                       // waits bfLow(t)+afLow(t); afHigh stays in flight
  // ---- ph1: rd bfHigh(t); stage (t+1).Ah1; fence: (t+1).B landed ----
#pragma unroll
  for (int n = 2; n < 4; ++n) {
    bf[n][0] = *(const short8*)(cB + bOff + n*2048 + slot0);
    bf[n][1] = *(const short8*)(cB + bOff + n*2048 + slot1);
  }
  if (stA) {
    gload16(sA1 + 2L*64*lA1, nAd + 2*4096 + wave*512);
    gload16(sA1 + 3L*64*lA1, nAd + 3*4096 + wave*512);
  }
  asm volatile("s_waitcnt vmcnt(4)" ::: "memory");   // drains (t+1).B (2-3 phases old)
  PHASE_MFMA(4, 4, 0)                       // waits afHigh; bfHigh stays in flight
  // ---- ph2: rd bfLow(t+1) from next buf ----
  if (rd) {
#pragma unroll
    for (int n = 0; n < 2; ++n) {
      bf[n][0] = *(const short8*)(nB + bOff + n*2048 + slot0);
      bf[n][1] = *(const short8*)(nB + bOff + n*2048 + slot1);
    }
    PHASE_MFMA(4, 0, 2)                     // waits bfHigh; bfLow(t+1) stays in flight
  } else {
    PHASE_MFMA(0, 0, 2)
  }
  // ---- ph3: stage (t+2).B into current B buf; fence: (t+1).A landed ----
  if (stB) {
#pragma unroll
    for (int i = 0; i < 4; ++i)
      gload16(sB2 + (long)i*64*lB2, cBd + i*4096 + wave*512);
    asm volatile("s_waitcnt vmcnt(4)" ::: "memory"); // drains (t+1).A, keeps (t+2).B
  } else {
    asm volatile("s_waitcnt vmcnt(0)" ::: "memory"); // tail: drain remaining (t+1).A
  }
  PHASE_MFMA(4, 4, 2)
}

// C[M,N] = A1[M,K1]@B1[N,K1]^T [+ A2[M,K2]@B2[N,K2]^T if SEG2].  nt must be even.
// EPI: 0 f32 | 1 silu->bf16 | 2 (*aux)->bf16
template<int EPI, bool SEG2>
__global__ __launch_bounds__(512, 2)
void gemm256(const unsigned short* __restrict__ Ag, int lda,
             const unsigned short* __restrict__ Bg, int ldb,
             void* __restrict__ Cg, int ldc,
             const unsigned short* __restrict__ Xg, int ldx,
             int K1,
             const unsigned short* __restrict__ A2g, int lda2,
             const unsigned short* __restrict__ B2g, int ldb2,
             int K2)
{
  __shared__ __align__(16) short As0[256*64], As1[256*64];
  __shared__ __align__(16) short Bs0[256*64], Bs1[256*64];
  int bx, by; xcd_swizzle(bx, by);
  const int tid = threadIdx.x;
  const int lane = tid & 63, wave = tid >> 6;
  const int q = lane >> 4, l15 = lane & 15;
  const int wm = wave >> 2, wn = wave & 3;

  const int arow = tid >> 3;
  const int kc8  = ((tid & 7) ^ (arow & 7)) * 8;

  const short* a1 = (const short*)Ag + (long)(by*256 + arow)*lda + kc8;
  const short* b1 = (const short*)Bg + (long)(bx*256 + arow)*ldb + kc8;
  const short* a2 = SEG2 ? (const short*)A2g + (long)(by*256 + arow)*lda2 + kc8 : (const short*)0;
  const short* b2 = SEG2 ? (const short*)B2g + (long)(bx*256 + arow)*ldb2 + kc8 : (const short*)0;
  const int nt1 = K1 >> 6, nt = SEG2 ? ((K1 + K2) >> 6) : (K1 >> 6);

  auto tA = [&](int T, const short*& p, int& ld) {
    if (!SEG2 || T < nt1) { p = a1 + T*64; ld = lda; } else { p = a2 + (T - nt1)*64; ld = lda2; }
  };
  auto tB = [&](int T, const short*& p, int& ld) {
    if (!SEG2 || T < nt1) { p = b1 + T*64; ld = ldb; } else { p = b2 + (T - nt1)*64; ld = ldb2; }
  };

  const int aOff  = (wm*128 + l15) * 128;   // bytes
  const int bOff  = (wn*64  + l15) * 128;
  const int l7    = l15 & 7;
  const int slot0 = ((0*4 + q) ^ l7) * 16;
  const int slot1 = ((1*4 + q) ^ l7) * 16;

  floatx4 acc[8][4] = {};
  short8 af[8][2], bf[4][2];

  // prologue: t0.A, t0.B, t1.B (12 gloads); t1.A staged by tile-0's ph0/ph1 (ring).
  stage_tile(a1, lda, As0, wave);
  stage_tile(b1, ldb, Bs0, wave);
  {
    const short *pb; int lb;
    tB(1, pb, lb);
    stage_tile(pb, lb, Bs1, wave);
  }
  asm volatile("s_waitcnt vmcnt(4)" ::: "memory");   // t0 landed; t1.B stays in flight
  __builtin_amdgcn_s_barrier();
  // pre-read bfLow(t0) (steady state reads bfLow(t) at ph(t-1,2))
#pragma unroll
  for (int n = 0; n < 2; ++n) {
    bf[n][0] = *(const short8*)((const char*)Bs0 + bOff + n*2048 + slot0);
    bf[n][1] = *(const short8*)((const char*)Bs0 + bOff + n*2048 + slot1);
  }

  for (int t = 0; t < nt; t += 2) {
    const short *pa, *pb, *qa, *qb; int la, lb, qla, qlb;
    const bool stA0 = (t+1) < nt, stB0 = (t+2) < nt;
    tA(t+1, pa, la); tB(t+2, pb, lb);
    ktile8((const char*)As0, (const char*)Bs0, (const char*)Bs1,
           As1, Bs0, pa, la, pb, lb, stA0, stB0, stA0, wave,
           aOff, bOff, slot0, slot1, af, bf, acc);
    const bool stA1 = (t+2) < nt, stB1 = (t+3) < nt;
    tA(t+2, qa, qla); tB(t+3, qb, qlb);
    ktile8((const char*)As1, (const char*)Bs1, (const char*)Bs0,
           As0, Bs1, qa, qla, qb, qlb, stA1, stB1, stA1, wave,
           aOff, bOff, slot0, slot1, af, bf, acc);
  }

#pragma unroll
  for (int m = 0; m < 8; ++m)
#pragma unroll
    for (int n = 0; n < 4; ++n)
#pragma unroll
      for (int r = 0; r < 4; ++r) {
        const int row = by*256 + wm*128 + m*16 + q*4 + r;
        const int col = bx*256 + wn*64  + n*16 + l15;
        const long ci = (long)row*ldc + col;
        float v = acc[m][n][r];
        if (EPI == 0) {
          ((float*)Cg)[ci] = v;
        } else if (EPI == 1) {
          v = v / (1.f + __expf(-v));
          ((unsigned short*)Cg)[ci] = f2b(v);
        } else if (EPI == 2) {
          float g = b2f(Xg[(long)row*ldx + col]);
          ((unsigned short*)Cg)[ci] = f2b(v * g);
        }
      }
}

// ---- pipelined K-loop (128-tile path for small-N / small-K GEMMs) ----
__device__ __forceinline__ void kloop_pipe(const short* Ap, int lda, const short* Bp, int ldb,
                                           short* As, short* Bs, int K,
                                           int tid, int q, int l15, int l7, int wm, int wn,
                                           floatx4 (*acc)[4])
{
  short8 pa[4], pb[4];
#pragma unroll
  for (int i = 0; i < 4; ++i) {
    pa[i] = *(const short8*)(Ap + (long)i*32*lda);
    pb[i] = *(const short8*)(Bp + (long)i*32*ldb);
  }
  for (int kt = 0; kt < K; kt += 64) {
#pragma unroll
    for (int i = 0; i < 4; ++i) {
      *(short8*)((char*)As + i*4096 + tid*16) = pa[i];
      *(short8*)((char*)Bs + i*4096 + tid*16) = pb[i];
    }
    __syncthreads();
    if (kt + 64 < K) {
#pragma unroll
      for (int i = 0; i < 4; ++i) {
        pa[i] = *(const short8*)(Ap + (long)i*32*lda + kt + 64);
        pb[i] = *(const short8*)(Bp + (long)i*32*ldb + kt + 64);
      }
    }
#pragma unroll
    for (int s = 0; s < 2; ++s) {
      short8 af[4], bf[4];
      const int slotoff = ((s*4 + q) ^ l7) * 16;
#pragma unroll
      for (int i = 0; i < 4; ++i) {
        af[i] = *(const short8*)((const char*)As + (wm*64 + i*16 + l15)*128 + slotoff);
        bf[i] = *(const short8*)((const char*)Bs + (wn*64 + i*16 + l15)*128 + slotoff);
      }
#pragma unroll
      for (int i = 0; i < 4; ++i)
#pragma unroll
        for (int j = 0; j < 4; ++j)
          acc[i][j] = __builtin_amdgcn_mfma_f32_16x16x32_bf16(af[i], bf[j], acc[i][j], 0, 0, 0);
    }
    __syncthreads();
  }
}

// ---------------- elementwise f32 -> bf16 cast ----------------
__global__ void cast_f32_bf16(const float* __restrict__ in, unsigned short* __restrict__ out, long n4) {
  long i = (long)blockIdx.x * blockDim.x + threadIdx.x;
  const long stride = (long)gridDim.x * blockDim.x;
  for (; i < n4; i += stride) {
    float4 v = ((const float4*)in)[i];
    ushort4 o;
    o.x = f2b(v.x); o.y = f2b(v.y); o.z = f2b(v.z); o.w = f2b(v.w);
    ((ushort4*)out)[i] = o;
  }
}

// ---------------- transpose+cast: in[R,C] f32 -> out[C,R] bf16 ----------------
__global__ void transpose_cast(const float* __restrict__ in, unsigned short* __restrict__ out,
                               int R, int C) {
  __shared__ float t[32][33];
  const int lx = threadIdx.x & 31, ly = threadIdx.x >> 5;   // 32x8
  const int r0 = blockIdx.y * 32, c0 = blockIdx.x * 32;
#pragma unroll
  for (int i = 0; i < 32; i += 8)
    t[ly + i][lx] = in[(long)(r0 + ly + i) * C + (c0 + lx)];
  __syncthreads();
#pragma unroll
  for (int i = 0; i < 32; i += 8)
    out[(long)(c0 + ly + i) * R + (r0 + lx)] = f2b(t[lx][ly + i]);
}

// ---------------- MFMA GEMM (128-tile): C[M,N] = A[M,K] @ Bt[N,K]^T ----------------
// EPI: 0 f32 | 1 silu->bf16 | 2 (*aux)->bf16 | 3 bf16 | 4 clip+-5,silu->bf16 | 6 0.1*v->bf16
template<int EPI>
__global__ __launch_bounds__(256)
void gemm_bt(const unsigned short* __restrict__ Ag, long sAz, int lda,
             const unsigned short* __restrict__ Bg, long sBz, int ldb,
             void* __restrict__ Cg, long sCz, int ldc,
             const unsigned short* __restrict__ Xg, long sXz, int ldx,
             int K)
{
  __shared__ __align__(16) short As[128*64];
  __shared__ __align__(16) short Bs[128*64];
  int bx, by; xcd_swizzle(bx, by);
  const int tid  = threadIdx.x;
  const int lane = tid & 63, wave = tid >> 6;
  const int q = lane >> 4, l15 = lane & 15, l7 = lane & 7;
  const int wm = wave & 1, wn = wave >> 1;

  const int arow = tid >> 3;                       // 0..31
  const int kc8  = ((tid & 7) ^ (arow & 7)) * 8;   // XOR-swizzled k-chunk

  const short* Ap = (const short*)Ag + (long)blockIdx.z*sAz + (long)(by*128 + arow)*lda + kc8;
  const short* Bp = (const short*)Bg + (long)blockIdx.z*sBz + (long)(bx*128 + arow)*ldb + kc8;

  floatx4 acc[4][4] = {};
  kloop_pipe(Ap, lda, Bp, ldb, As, Bs, K, tid, q, l15, l7, wm, wn, acc);

  const long cz = (long)blockIdx.z * sCz;
  const long xz = (long)blockIdx.z * sXz;
#pragma unroll
  for (int i = 0; i < 4; ++i)
#pragma unroll
    for (int j = 0; j < 4; ++j)
#pragma unroll
      for (int r = 0; r < 4; ++r) {
        const int row = by*128 + wm*64 + i*16 + q*4 + r;
        const int col = bx*128 + wn*64 + j*16 + l15;
        const long ci = cz + (long)row*ldc + col;
        float v = acc[i][j][r];
        if (EPI == 0) {
          ((float*)Cg)[ci] = v;
        } else if (EPI == 1) {
          v = v / (1.f + __expf(-v));
          ((unsigned short*)Cg)[ci] = f2b(v);
        } else if (EPI == 2) {
          float g = b2f(Xg[xz + (long)row*ldx + col]);
          ((unsigned short*)Cg)[ci] = f2b(v * g);
        } else if (EPI == 3) {
          ((unsigned short*)Cg)[ci] = f2b(v);
        } else if (EPI == 4) {
          v = fminf(fmaxf(v, -5.f), 5.f);
          v = v / (1.f + __expf(-v));
          ((unsigned short*)Cg)[ci] = f2b(v);
        } else if (EPI == 6) {
          ((unsigned short*)Cg)[ci] = f2b(0.1f * v);
        }
      }
}

// ---------------- LayerNorm over A=128 (one wave per row); X2 = split-K partial ----------------
__global__ void ln_rows(const float* __restrict__ X, const float* __restrict__ X2,
                        const float* __restrict__ g,
                        const float* __restrict__ b, unsigned short* __restrict__ lnout,
                        unsigned short* __restrict__ rawout, unsigned short* __restrict__ tout)
{
  const int lane = threadIdx.x & 63, wave = threadIdx.x >> 6;
  const long t = (long)blockIdx.x*4 + wave;
  const float* x  = X  + t*AA;
  const float* x2 = X2 + t*AA;
  float x0 = x[lane]      + x2[lane];
  float x1 = x[lane + 64] + x2[lane + 64];
  float s = x0 + x1, s2 = x0*x0 + x1*x1;
#pragma unroll
  for (int m = 1; m < 64; m <<= 1) {
    s  += __shfl_xor(s, m, 64);
    s2 += __shfl_xor(s2, m, 64);
  }
  float mean = s * (1.f/AA);
  float inv  = rsqrtf(s2*(1.f/AA) - mean*mean + 1e-5f);
  float y0 = (x0 - mean)*inv*g[lane] + b[lane];
  float y1 = (x1 - mean)*inv*g[lane+64] + b[lane+64];
  lnout[t*AA + lane]      = f2b(y0);
  lnout[t*AA + lane + 64] = f2b(y1);
  if (rawout) { rawout[t*AA+lane] = f2b(x0); rawout[t*AA+lane+64] = f2b(x1); }
  if (tout) {
    const long bb = t >> 11, si = t & (SS-1);
    tout[bb*(long)AA*SS + (long)lane*SS + si]      = f2b(y0);
    tout[bb*(long)AA*SS + (long)(lane+64)*SS + si] = f2b(y1);
  }
}

// ---------------- per-token expert select (last positive wins) + LN ----------------
__global__ void expert_select_ln(const float* __restrict__ ew, const unsigned short* __restrict__ eall,
                                 const float* __restrict__ eg, const float* __restrict__ ebias,
                                 unsigned short* __restrict__ Fc)
{
  const int lane = threadIdx.x & 63, wave = threadIdx.x >> 6;
  const long t = (long)blockIdx.x*4 + wave;
  const float* w = ew + t*EE;
  int ie = -1;
#pragma unroll
  for (int i = 0; i < EE; ++i) if (w[i] > 0.f) ie = i;
  unsigned short o0 = 0, o1 = 0;
  if (ie >= 0) {
    float x0 = b2f(eall[t*(EE*AA) + ie*AA + lane]);
    float x1 = b2f(eall[t*(EE*AA) + ie*AA + lane + 64]);
    float s = x0 + x1, s2 = x0*x0 + x1*x1;
#pragma unroll
    for (int m = 1; m < 64; m <<= 1) { s += __shfl_xor(s, m, 64); s2 += __shfl_xor(s2, m, 64); }
    float mean = s * (1.f/AA);
    float inv  = rsqrtf(s2*(1.f/AA) - mean*mean + 1e-5f);
    o0 = f2b((x0-mean)*inv*eg[ie*AA+lane]    + ebias[ie*AA+lane]);
    o1 = f2b((x1-mean)*inv*eg[ie*AA+lane+64] + ebias[ie*AA+lane+64]);
  }
  Fc[t*256 + lane]      = o0;
  Fc[t*256 + lane + 64] = o1;
}

extern "C" void kernel_launch(void* const* d_in, const int* in_sizes, int n_in,
                              void* d_out, int out_size, void* d_ws, size_t ws_size,
                              hipStream_t stream)
{
  const float* x       = (const float*)d_in[0];
  const float* ew      = (const float*)d_in[1];
  const float* w_up    = (const float*)d_in[2];
  const float* w_gate  = (const float*)d_in[3];
  const float* w_down  = (const float*)d_in[4];
  const float* w_pre   = (const float*)d_in[5];
  const float* w_post  = (const float*)d_in[6];
  const float* an_g    = (const float*)d_in[7];
  const float* an_b    = (const float*)d_in[8];
  const float* w_aproj = (const float*)d_in[9];
  const float* w_exp   = (const float*)d_in[10];
  const float* eln_g   = (const float*)d_in[11];
  const float* eln_b   = (const float*)d_in[12];
  const float* w_eproj = (const float*)d_in[13];
  const float* w_out   = (const float*)d_in[14];

  char* ws = (char*)d_ws;
  size_t off = 0;
  auto take = [&](size_t bytes) { char* p = ws + off; off += (bytes + 255) & ~(size_t)255; return p; };

  unsigned short* Sc    = (unsigned short*)take((size_t)BB*SS*SS*2);
  unsigned short* xb    = Sc;
  unsigned short* eall  = (unsigned short*)((char*)Sc + (size_t)TOK*DD*2);
  unsigned short* hid   = (unsigned short*)take((size_t)TOK*HH*2);
  float*          pre   = (float*)take((size_t)TOK*AA*4*2);    // 2 split-K slabs
  float*          postA = (float*)take((size_t)TOK*AA*4*2);    // 2 split-K slabs
  unsigned short* Fc    = (unsigned short*)take((size_t)TOK*256*2);
  unsigned short* ain   = (unsigned short*)take((size_t)TOK*AA*2);
  unsigned short* ainT  = (unsigned short*)take((size_t)TOK*AA*2);
  unsigned short* aout  = (unsigned short*)take((size_t)TOK*AA*2);
  unsigned short* preb  = (unsigned short*)take((size_t)TOK*AA*2);
  unsigned short* wgb   = (unsigned short*)take((size_t)HH*DD*2);
  unsigned short* wub   = (unsigned short*)take((size_t)HH*DD*2);
  unsigned short* wdb   = (unsigned short*)take((size_t)DD*HH*2);
  unsigned short* wpostb= (unsigned short*)take((size_t)AA*HH*2);
  unsigned short* wpreb = (unsigned short*)take((size_t)AA*DD*2);
  unsigned short* wexpb = (unsigned short*)take((size_t)EE*AA*AA*2);
  unsigned short* Wc    = (unsigned short*)take((size_t)DD*256*2);
  (void)ws_size; (void)in_sizes; (void)n_in; (void)out_size;

  unsigned short* woutb  = hid;                               // [1024,2048] bf16
  unsigned short* btT    = hid + (size_t)DD*HH;               // [2,128,2048] bf16
  unsigned short* eprojT = btT;
  unsigned short* aprojT = btT + (size_t)AA*HH;

  // casts
  cast_f32_bf16<<<1024, 256, 0, stream>>>(x,      xb,     (long)TOK*DD/4);
  cast_f32_bf16<<<256,  256, 0, stream>>>(w_gate, wgb,    (long)HH*DD/4);
  cast_f32_bf16<<<256,  256, 0, stream>>>(w_up,   wub,    (long)HH*DD/4);
  cast_f32_bf16<<<256,  256, 0, stream>>>(w_down, wdb,    (long)DD*HH/4);
  cast_f32_bf16<<<256,  256, 0, stream>>>(w_out,  woutb,  (long)DD*HH/4);
  cast_f32_bf16<<<64,   256, 0, stream>>>(w_post, wpostb, (long)AA*HH/4);
  cast_f32_bf16<<<32,   256, 0, stream>>>(w_pre,  wpreb,  (long)AA*DD/4);
  cast_f32_bf16<<<32,   256, 0, stream>>>(w_exp,  wexpb,  (long)EE*AA*AA/4);

  // transpose+cast the fold B operands: [H,A] f32 -> [A,H] bf16
  transpose_cast<<<dim3(AA/32, HH/32), 256, 0, stream>>>(w_eproj, eprojT, HH, AA);
  transpose_cast<<<dim3(AA/32, HH/32), 256, 0, stream>>>(w_aproj, aprojT, HH, AA);

  // folded matrices: z=0: 0.1*w_out@w_eproj -> Wc[:,0:128], z=1: 0.1*w_down@w_aproj -> Wc[:,128:256]
  gemm_bt<6><<<dim3(1, DD/128, 2), 256, 0, stream>>>(
      woutb, (long)(wdb - woutb), HH,
      eprojT, (long)AA*HH, HH,
      Wc, AA, 256, nullptr, 0, 0, HH);

  // gate (silu) then up (*gate), in place into hid — 256² counted-wait path
  gemm256<1, false><<<dim3(HH/256, TOK/256), 512, 0, stream>>>(
      xb, DD, wgb, DD, hid, HH, nullptr, 0, DD, nullptr, 0, nullptr, 0, 0);
  gemm256<2, false><<<dim3(HH/256, TOK/256), 512, 0, stream>>>(
      xb, DD, wub, DD, hid, HH, hid, HH, DD, nullptr, 0, nullptr, 0, 0);

  // pre = x @ w_pre^T, split-K=2 (z = K-half) into two f32 slabs, summed in ln_rows
  gemm_bt<0><<<dim3(1, TOK/128, 2), 256, 0, stream>>>(
      xb, DD/2, DD, wpreb, DD/2, DD, pre, (long)TOK*AA, AA, nullptr, 0, 0, DD/2);
  ln_rows<<<TOK/4, 256, 0, stream>>>(pre, pre + (size_t)TOK*AA, an_g, an_b, ain, preb, ainT);

  // all-expert mix + per-token select/LN -> Fc[:,0:128]
  gemm_bt<3><<<dim3((EE*AA)/128, TOK/128, 1), 256, 0, stream>>>(preb,0,AA, wexpb,0,AA, eall,0,EE*AA, nullptr,0,0, AA);
  expert_select_ln<<<TOK/4, 256, 0, stream>>>(ew, eall, eln_g, eln_b, Fc);

  // adapt_out = LN(hidden @ w_post^T), split-K=2
  gemm_bt<0><<<dim3(1, TOK/128, 2), 256, 0, stream>>>(
      hid, HH/2, HH, wpostb, HH/2, HH, postA, (long)TOK*AA, AA, nullptr, 0, 0, HH/2);
  ln_rows<<<TOK/4, 256, 0, stream>>>(postA, postA + (size_t)TOK*AA, an_g, an_b, aout, nullptr, nullptr);

  // scores: Sc[z] = silu(clip(ain[z] @ aout[z]^T))   (K = A = 128)
  gemm_bt<4><<<dim3(SS/128, SS/128, BB), 256, 0, stream>>>(ain,(long)SS*AA,AA, aout,(long)SS*AA,AA,
                                                           Sc,(long)SS*SS,SS, nullptr,0,0, AA);
  // adapt: Fc[:,128:256] = Sc[z] @ ainT[z]^T
  gemm_bt<3><<<dim3(1, SS/128, BB), 256, 0, stream>>>(Sc,(long)SS*SS,SS, ainT,(long)AA*SS,SS,
                                                      Fc+AA,(long)SS*256,256, nullptr,0,0, SS);
  // out = hid@wdb^T + Fc@Wc'^T  (fp32, Wc' pre-scaled 0.1) — fused-K 256²
  gemm256<0, true><<<dim3(DD/256, TOK/256), 512, 0, stream>>>(
      hid, HH, wdb, HH, (float*)d_out, DD, nullptr, 0, HH, Fc, 256, Wc, 256, 256);
}

// Round 4
// 572.218 us; speedup vs baseline: 1.9753x; 1.9753x over previous
//
#include <hip/hip_runtime.h>

#define TOK 16384
#define DD 1024
#define HH 2048
#define AA 128
#define EE 8
#define SS 2048
#define BB 8

typedef __attribute__((ext_vector_type(8))) short short8;
typedef __attribute__((ext_vector_type(4))) float floatx4;

__device__ __forceinline__ unsigned short f2b(float f) {
  unsigned u = __float_as_uint(f);
  u += 0x7fff + ((u >> 16) & 1);          // RNE
  return (unsigned short)(u >> 16);
}
__device__ __forceinline__ float b2f(unsigned short h) {
  return __uint_as_float(((unsigned)h) << 16);
}

__device__ __forceinline__ void xcd_swizzle(int& bx, int& by) {
  const int nbx = gridDim.x, nby = gridDim.y;
  if ((nby & 7) == 0) {
    const int L = blockIdx.y * nbx + blockIdx.x;
    const int xcd = L & 7, idx = L >> 3;
    bx = idx % nbx;
    by = (xcd * (nby >> 3)) + idx / nbx;
  } else {
    bx = blockIdx.x; by = blockIdx.y;
  }
}

// ================= 256x256 GEMM: reads feed same-phase MFMA (counted lgkm) =================
// 512 thr = 8 waves (2M x 4N), BK=64, LDS 128KiB. Per phase: {<=12 ds_read -> MFMA quadrant
// via compiler-counted lgkmcnt; 2 global_load_lds staged; lgkm(0) (free, post-MFMA); barrier}.
// LDS pipe drains UNDER the MFMA cluster (no wait between read-issue and MFMA).
// Staging ring: A(t+1) halves at P0/P1 (other buf), B(t+2) halves at P2/P3 (current buf);
// one counted vmcnt(4) per tile at P3 (drains tile t+1 fully, keeps B(t+2) in flight).
// WAR: each overwritten half last read >=1 barrier before its stage phase (A: read P0/P2,
// staged next tile's P0/P1; B: read P0/P1, staged P2/P3).

__device__ __forceinline__ void gload16(const short* g, short* l) {
  __builtin_amdgcn_global_load_lds((__attribute__((address_space(1))) void*)(void*)g,
                                   (__attribute__((address_space(3))) void*)l, 16, 0, 0);
}

// stage half h (rows h*128..h*128+127) of a 256x64 tile: 2 gloads (i = 2h, 2h+1)
__device__ __forceinline__ void stage_half(const short* src, int ld, short* dst, int wave, int h) {
  gload16(src + (long)(2*h)  *64*ld, dst + (2*h)  *4096 + wave*512);
  gload16(src + (long)(2*h+1)*64*ld, dst + (2*h+1)*4096 + wave*512);
}

#define MFMA_Q(M0, N0)                                                                   \
  __builtin_amdgcn_s_setprio(1);                                                         \
  _Pragma("unroll")                                                                      \
  for (int kk = 0; kk < 2; ++kk)                                                         \
    _Pragma("unroll")                                                                    \
    for (int m = 0; m < 4; ++m)                                                          \
      _Pragma("unroll")                                                                  \
      for (int n = 0; n < 2; ++n)                                                        \
        acc[M0+m][N0+n] = __builtin_amdgcn_mfma_f32_16x16x32_bf16(af[M0+m][kk], bf[N0+n][kk], acc[M0+m][N0+n], 0, 0, 0); \
  __builtin_amdgcn_s_setprio(0);

#define PHASE_END                                                                        \
  asm volatile("s_waitcnt lgkmcnt(0)" ::: "memory");                                     \
  __builtin_amdgcn_s_barrier();                                                          \
  asm volatile("" ::: "memory");

__device__ __forceinline__ void ktile8(const char* cA, const char* cB,   // current bufs
                                       short* nAd, short* cBd,           // stage dests
                                       const short* sA1, int lA1,        // A(t+1) src
                                       const short* sB2, int lB2,        // B(t+2) src
                                       bool stA, bool stB, int wave,
                                       int aOff, int bOff, int slot0, int slot1,
                                       floatx4 (*acc)[4])
{
  short8 af[8][2], bf[4][2];
  // ---- P0: rd af[0-3]+bf[0-1]; stage A(t+1)h0; MFMA (m0-3, n0-1) ----
#pragma unroll
  for (int m = 0; m < 4; ++m) {
    af[m][0] = *(const short8*)(cA + aOff + m*2048 + slot0);
    af[m][1] = *(const short8*)(cA + aOff + m*2048 + slot1);
  }
#pragma unroll
  for (int n = 0; n < 2; ++n) {
    bf[n][0] = *(const short8*)(cB + bOff + n*2048 + slot0);
    bf[n][1] = *(const short8*)(cB + bOff + n*2048 + slot1);
  }
  if (stA) stage_half(sA1, lA1, nAd, wave, 0);
  MFMA_Q(0, 0)
  PHASE_END
  // ---- P1: rd bf[2-3]; stage A(t+1)h1; MFMA (m0-3, n2-3) ----
#pragma unroll
  for (int n = 2; n < 4; ++n) {
    bf[n][0] = *(const short8*)(cB + bOff + n*2048 + slot0);
    bf[n][1] = *(const short8*)(cB + bOff + n*2048 + slot1);
  }
  if (stA) stage_half(sA1, lA1, nAd, wave, 1);
  MFMA_Q(0, 2)
  PHASE_END
  // ---- P2: rd af[4-7]; stage B(t+2)h0; MFMA (m4-7, n0-1) ----
#pragma unroll
  for (int m = 4; m < 8; ++m) {
    af[m][0] = *(const short8*)(cA + aOff + m*2048 + slot0);
    af[m][1] = *(const short8*)(cA + aOff + m*2048 + slot1);
  }
  if (stB) stage_half(sB2, lB2, cBd, wave, 0);
  MFMA_Q(4, 0)
  PHASE_END
  // ---- P3: stage B(t+2)h1; MFMA (m4-7, n2-3); tile-boundary counted vmcnt ----
  if (stB) stage_half(sB2, lB2, cBd, wave, 1);
  MFMA_Q(4, 2)
  asm volatile("s_waitcnt lgkmcnt(0)" ::: "memory");
  if (stB) asm volatile("s_waitcnt vmcnt(4)" ::: "memory");  // drains tile t+1; keeps B(t+2)
  else     asm volatile("s_waitcnt vmcnt(0)" ::: "memory");  // tail: drain all
  __builtin_amdgcn_s_barrier();
  asm volatile("" ::: "memory");
}

// C[M,N] = A1[M,K1]@B1[N,K1]^T [+ A2[M,K2]@B2[N,K2]^T if SEG2].  nt must be even.
// EPI: 0 f32 | 1 silu->bf16 | 2 (*aux)->bf16
template<int EPI, bool SEG2>
__global__ __launch_bounds__(512, 2)
void gemm256(const unsigned short* __restrict__ Ag, int lda,
             const unsigned short* __restrict__ Bg, int ldb,
             void* __restrict__ Cg, int ldc,
             const unsigned short* __restrict__ Xg, int ldx,
             int K1,
             const unsigned short* __restrict__ A2g, int lda2,
             const unsigned short* __restrict__ B2g, int ldb2,
             int K2)
{
  __shared__ __align__(16) short As0[256*64], As1[256*64];
  __shared__ __align__(16) short Bs0[256*64], Bs1[256*64];
  int bx, by; xcd_swizzle(bx, by);
  const int tid = threadIdx.x;
  const int lane = tid & 63, wave = tid >> 6;
  const int q = lane >> 4, l15 = lane & 15;
  const int wm = wave >> 2, wn = wave & 3;

  const int arow = tid >> 3;
  const int kc8  = ((tid & 7) ^ (arow & 7)) * 8;

  const short* a1 = (const short*)Ag + (long)(by*256 + arow)*lda + kc8;
  const short* b1 = (const short*)Bg + (long)(bx*256 + arow)*ldb + kc8;
  const short* a2 = SEG2 ? (const short*)A2g + (long)(by*256 + arow)*lda2 + kc8 : (const short*)0;
  const short* b2 = SEG2 ? (const short*)B2g + (long)(bx*256 + arow)*ldb2 + kc8 : (const short*)0;
  const int nt1 = K1 >> 6, nt = SEG2 ? ((K1 + K2) >> 6) : (K1 >> 6);

  auto tA = [&](int T, const short*& p, int& ld) {
    if (!SEG2 || T < nt1) { p = a1 + T*64; ld = lda; } else { p = a2 + (T - nt1)*64; ld = lda2; }
  };
  auto tB = [&](int T, const short*& p, int& ld) {
    if (!SEG2 || T < nt1) { p = b1 + T*64; ld = ldb; } else { p = b2 + (T - nt1)*64; ld = ldb2; }
  };

  const int aOff  = (wm*128 + l15) * 128;   // bytes
  const int bOff  = (wn*64  + l15) * 128;
  const int l7    = l15 & 7;
  const int slot0 = ((0*4 + q) ^ l7) * 16;
  const int slot1 = ((1*4 + q) ^ l7) * 16;

  floatx4 acc[8][4] = {};

  // prologue: t0.A, t0.B -> buf0; t1.B -> buf1 (t1.A staged by tile0 P0/P1).
  stage_half(a1, lda, As0, wave, 0); stage_half(a1, lda, As0, wave, 1);
  stage_half(b1, ldb, Bs0, wave, 0); stage_half(b1, ldb, Bs0, wave, 1);
  {
    const short *pb; int lb;
    tB(1, pb, lb);
    stage_half(pb, lb, Bs1, wave, 0); stage_half(pb, lb, Bs1, wave, 1);
  }
  asm volatile("s_waitcnt vmcnt(4)" ::: "memory");   // t0 landed; t1.B stays in flight
  __builtin_amdgcn_s_barrier();
  asm volatile("" ::: "memory");

  for (int t = 0; t < nt; t += 2) {
    const short *sa, *sb; int la, lb;
    // even tile t: bufs (As0,Bs0); stage A(t+1)->As1, B(t+2)->Bs0
    {
      const bool stA = (t+1) < nt, stB = (t+2) < nt;
      sa = a1; la = lda; sb = b1; lb = ldb;
      if (stA) tA(t+1, sa, la);
      if (stB) tB(t+2, sb, lb);
      ktile8((const char*)As0, (const char*)Bs0, As1, Bs0,
             sa, la, sb, lb, stA, stB, wave, aOff, bOff, slot0, slot1, acc);
    }
    // odd tile t+1: bufs (As1,Bs1); stage A(t+2)->As0, B(t+3)->Bs1
    {
      const bool stA = (t+2) < nt, stB = (t+3) < nt;
      sa = a1; la = lda; sb = b1; lb = ldb;
      if (stA) tA(t+2, sa, la);
      if (stB) tB(t+3, sb, lb);
      ktile8((const char*)As1, (const char*)Bs1, As0, Bs1,
             sa, la, sb, lb, stA, stB, wave, aOff, bOff, slot0, slot1, acc);
    }
  }

#pragma unroll
  for (int m = 0; m < 8; ++m)
#pragma unroll
    for (int n = 0; n < 4; ++n)
#pragma unroll
      for (int r = 0; r < 4; ++r) {
        const int row = by*256 + wm*128 + m*16 + q*4 + r;
        const int col = bx*256 + wn*64  + n*16 + l15;
        const long ci = (long)row*ldc + col;
        float v = acc[m][n][r];
        if (EPI == 0) {
          ((float*)Cg)[ci] = v;
        } else if (EPI == 1) {
          v = v / (1.f + __expf(-v));
          ((unsigned short*)Cg)[ci] = f2b(v);
        } else if (EPI == 2) {
          float g = b2f(Xg[(long)row*ldx + col]);
          ((unsigned short*)Cg)[ci] = f2b(v * g);
        }
      }
}

// ---- pipelined K-loop (128-tile path for small-N / small-K GEMMs) ----
__device__ __forceinline__ void kloop_pipe(const short* Ap, int lda, const short* Bp, int ldb,
                                           short* As, short* Bs, int K,
                                           int tid, int q, int l15, int l7, int wm, int wn,
                                           floatx4 (*acc)[4])
{
  short8 pa[4], pb[4];
#pragma unroll
  for (int i = 0; i < 4; ++i) {
    pa[i] = *(const short8*)(Ap + (long)i*32*lda);
    pb[i] = *(const short8*)(Bp + (long)i*32*ldb);
  }
  for (int kt = 0; kt < K; kt += 64) {
#pragma unroll
    for (int i = 0; i < 4; ++i) {
      *(short8*)((char*)As + i*4096 + tid*16) = pa[i];
      *(short8*)((char*)Bs + i*4096 + tid*16) = pb[i];
    }
    __syncthreads();
    if (kt + 64 < K) {
#pragma unroll
      for (int i = 0; i < 4; ++i) {
        pa[i] = *(const short8*)(Ap + (long)i*32*lda + kt + 64);
        pb[i] = *(const short8*)(Bp + (long)i*32*ldb + kt + 64);
      }
    }
#pragma unroll
    for (int s = 0; s < 2; ++s) {
      short8 af[4], bf[4];
      const int slotoff = ((s*4 + q) ^ l7) * 16;
#pragma unroll
      for (int i = 0; i < 4; ++i) {
        af[i] = *(const short8*)((const char*)As + (wm*64 + i*16 + l15)*128 + slotoff);
        bf[i] = *(const short8*)((const char*)Bs + (wn*64 + i*16 + l15)*128 + slotoff);
      }
#pragma unroll
      for (int i = 0; i < 4; ++i)
#pragma unroll
        for (int j = 0; j < 4; ++j)
          acc[i][j] = __builtin_amdgcn_mfma_f32_16x16x32_bf16(af[i], bf[j], acc[i][j], 0, 0, 0);
    }
    __syncthreads();
  }
}

// ---------------- elementwise f32 -> bf16 cast ----------------
__global__ void cast_f32_bf16(const float* __restrict__ in, unsigned short* __restrict__ out, long n4) {
  long i = (long)blockIdx.x * blockDim.x + threadIdx.x;
  const long stride = (long)gridDim.x * blockDim.x;
  for (; i < n4; i += stride) {
    float4 v = ((const float4*)in)[i];
    ushort4 o;
    o.x = f2b(v.x); o.y = f2b(v.y); o.z = f2b(v.z); o.w = f2b(v.w);
    ((ushort4*)out)[i] = o;
  }
}

// ---------------- transpose+cast: in[R,C] f32 -> out[C,R] bf16 ----------------
__global__ void transpose_cast(const float* __restrict__ in, unsigned short* __restrict__ out,
                               int R, int C) {
  __shared__ float t[32][33];
  const int lx = threadIdx.x & 31, ly = threadIdx.x >> 5;   // 32x8
  const int r0 = blockIdx.y * 32, c0 = blockIdx.x * 32;
#pragma unroll
  for (int i = 0; i < 32; i += 8)
    t[ly + i][lx] = in[(long)(r0 + ly + i) * C + (c0 + lx)];
  __syncthreads();
#pragma unroll
  for (int i = 0; i < 32; i += 8)
    out[(long)(c0 + ly + i) * R + (r0 + lx)] = f2b(t[lx][ly + i]);
}

// ---------------- MFMA GEMM (128-tile): C[M,N] = A[M,K] @ Bt[N,K]^T ----------------
// EPI: 0 f32 | 1 silu->bf16 | 2 (*aux)->bf16 | 3 bf16 | 4 clip+-5,silu->bf16 | 6 0.1*v->bf16
template<int EPI>
__global__ __launch_bounds__(256)
void gemm_bt(const unsigned short* __restrict__ Ag, long sAz, int lda,
             const unsigned short* __restrict__ Bg, long sBz, int ldb,
             void* __restrict__ Cg, long sCz, int ldc,
             const unsigned short* __restrict__ Xg, long sXz, int ldx,
             int K)
{
  __shared__ __align__(16) short As[128*64];
  __shared__ __align__(16) short Bs[128*64];
  int bx, by; xcd_swizzle(bx, by);
  const int tid  = threadIdx.x;
  const int lane = tid & 63, wave = tid >> 6;
  const int q = lane >> 4, l15 = lane & 15, l7 = lane & 7;
  const int wm = wave & 1, wn = wave >> 1;

  const int arow = tid >> 3;                       // 0..31
  const int kc8  = ((tid & 7) ^ (arow & 7)) * 8;   // XOR-swizzled k-chunk

  const short* Ap = (const short*)Ag + (long)blockIdx.z*sAz + (long)(by*128 + arow)*lda + kc8;
  const short* Bp = (const short*)Bg + (long)blockIdx.z*sBz + (long)(bx*128 + arow)*ldb + kc8;

  floatx4 acc[4][4] = {};
  kloop_pipe(Ap, lda, Bp, ldb, As, Bs, K, tid, q, l15, l7, wm, wn, acc);

  const long cz = (long)blockIdx.z * sCz;
  const long xz = (long)blockIdx.z * sXz;
#pragma unroll
  for (int i = 0; i < 4; ++i)
#pragma unroll
    for (int j = 0; j < 4; ++j)
#pragma unroll
      for (int r = 0; r < 4; ++r) {
        const int row = by*128 + wm*64 + i*16 + q*4 + r;
        const int col = bx*128 + wn*64 + j*16 + l15;
        const long ci = cz + (long)row*ldc + col;
        float v = acc[i][j][r];
        if (EPI == 0) {
          ((float*)Cg)[ci] = v;
        } else if (EPI == 1) {
          v = v / (1.f + __expf(-v));
          ((unsigned short*)Cg)[ci] = f2b(v);
        } else if (EPI == 2) {
          float g = b2f(Xg[xz + (long)row*ldx + col]);
          ((unsigned short*)Cg)[ci] = f2b(v * g);
        } else if (EPI == 3) {
          ((unsigned short*)Cg)[ci] = f2b(v);
        } else if (EPI == 4) {
          v = fminf(fmaxf(v, -5.f), 5.f);
          v = v / (1.f + __expf(-v));
          ((unsigned short*)Cg)[ci] = f2b(v);
        } else if (EPI == 6) {
          ((unsigned short*)Cg)[ci] = f2b(0.1f * v);
        }
      }
}

// ---------------- LayerNorm over A=128 (one wave per row); X2 = split-K partial ----------------
__global__ void ln_rows(const float* __restrict__ X, const float* __restrict__ X2,
                        const float* __restrict__ g,
                        const float* __restrict__ b, unsigned short* __restrict__ lnout,
                        unsigned short* __restrict__ rawout, unsigned short* __restrict__ tout)
{
  const int lane = threadIdx.x & 63, wave = threadIdx.x >> 6;
  const long t = (long)blockIdx.x*4 + wave;
  const float* x  = X  + t*AA;
  const float* x2 = X2 + t*AA;
  float x0 = x[lane]      + x2[lane];
  float x1 = x[lane + 64] + x2[lane + 64];
  float s = x0 + x1, s2 = x0*x0 + x1*x1;
#pragma unroll
  for (int m = 1; m < 64; m <<= 1) {
    s  += __shfl_xor(s, m, 64);
    s2 += __shfl_xor(s2, m, 64);
  }
  float mean = s * (1.f/AA);
  float inv  = rsqrtf(s2*(1.f/AA) - mean*mean + 1e-5f);
  float y0 = (x0 - mean)*inv*g[lane] + b[lane];
  float y1 = (x1 - mean)*inv*g[lane+64] + b[lane+64];
  lnout[t*AA + lane]      = f2b(y0);
  lnout[t*AA + lane + 64] = f2b(y1);
  if (rawout) { rawout[t*AA+lane] = f2b(x0); rawout[t*AA+lane+64] = f2b(x1); }
  if (tout) {
    const long bb = t >> 11, si = t & (SS-1);
    tout[bb*(long)AA*SS + (long)lane*SS + si]      = f2b(y0);
    tout[bb*(long)AA*SS + (long)(lane+64)*SS + si] = f2b(y1);
  }
}

// ---------------- per-token expert select (last positive wins) + LN ----------------
__global__ void expert_select_ln(const float* __restrict__ ew, const unsigned short* __restrict__ eall,
                                 const float* __restrict__ eg, const float* __restrict__ ebias,
                                 unsigned short* __restrict__ Fc)
{
  const int lane = threadIdx.x & 63, wave = threadIdx.x >> 6;
  const long t = (long)blockIdx.x*4 + wave;
  const float* w = ew + t*EE;
  int ie = -1;
#pragma unroll
  for (int i = 0; i < EE; ++i) if (w[i] > 0.f) ie = i;
  unsigned short o0 = 0, o1 = 0;
  if (ie >= 0) {
    float x0 = b2f(eall[t*(EE*AA) + ie*AA + lane]);
    float x1 = b2f(eall[t*(EE*AA) + ie*AA + lane + 64]);
    float s = x0 + x1, s2 = x0*x0 + x1*x1;
#pragma unroll
    for (int m = 1; m < 64; m <<= 1) { s += __shfl_xor(s, m, 64); s2 += __shfl_xor(s2, m, 64); }
    float mean = s * (1.f/AA);
    float inv  = rsqrtf(s2*(1.f/AA) - mean*mean + 1e-5f);
    o0 = f2b((x0-mean)*inv*eg[ie*AA+lane]    + ebias[ie*AA+lane]);
    o1 = f2b((x1-mean)*inv*eg[ie*AA+lane+64] + ebias[ie*AA+lane+64]);
  }
  Fc[t*256 + lane]      = o0;
  Fc[t*256 + lane + 64] = o1;
}

extern "C" void kernel_launch(void* const* d_in, const int* in_sizes, int n_in,
                              void* d_out, int out_size, void* d_ws, size_t ws_size,
                              hipStream_t stream)
{
  const float* x       = (const float*)d_in[0];
  const float* ew      = (const float*)d_in[1];
  const float* w_up    = (const float*)d_in[2];
  const float* w_gate  = (const float*)d_in[3];
  const float* w_down  = (const float*)d_in[4];
  const float* w_pre   = (const float*)d_in[5];
  const float* w_post  = (const float*)d_in[6];
  const float* an_g    = (const float*)d_in[7];
  const float* an_b    = (const float*)d_in[8];
  const float* w_aproj = (const float*)d_in[9];
  const float* w_exp   = (const float*)d_in[10];
  const float* eln_g   = (const float*)d_in[11];
  const float* eln_b   = (const float*)d_in[12];
  const float* w_eproj = (const float*)d_in[13];
  const float* w_out   = (const float*)d_in[14];

  char* ws = (char*)d_ws;
  size_t off = 0;
  auto take = [&](size_t bytes) { char* p = ws + off; off += (bytes + 255) & ~(size_t)255; return p; };

  unsigned short* Sc    = (unsigned short*)take((size_t)BB*SS*SS*2);
  unsigned short* xb    = Sc;
  unsigned short* eall  = (unsigned short*)((char*)Sc + (size_t)TOK*DD*2);
  unsigned short* hid   = (unsigned short*)take((size_t)TOK*HH*2);
  float*          pre   = (float*)take((size_t)TOK*AA*4*2);    // 2 split-K slabs
  float*          postA = (float*)take((size_t)TOK*AA*4*2);    // 2 split-K slabs
  unsigned short* Fc    = (unsigned short*)take((size_t)TOK*256*2);
  unsigned short* ain   = (unsigned short*)take((size_t)TOK*AA*2);
  unsigned short* ainT  = (unsigned short*)take((size_t)TOK*AA*2);
  unsigned short* aout  = (unsigned short*)take((size_t)TOK*AA*2);
  unsigned short* preb  = (unsigned short*)take((size_t)TOK*AA*2);
  unsigned short* wgb   = (unsigned short*)take((size_t)HH*DD*2);
  unsigned short* wub   = (unsigned short*)take((size_t)HH*DD*2);
  unsigned short* wdb   = (unsigned short*)take((size_t)DD*HH*2);
  unsigned short* wpostb= (unsigned short*)take((size_t)AA*HH*2);
  unsigned short* wpreb = (unsigned short*)take((size_t)AA*DD*2);
  unsigned short* wexpb = (unsigned short*)take((size_t)EE*AA*AA*2);
  unsigned short* Wc    = (unsigned short*)take((size_t)DD*256*2);
  (void)ws_size; (void)in_sizes; (void)n_in; (void)out_size;

  unsigned short* woutb  = hid;                               // [1024,2048] bf16
  unsigned short* btT    = hid + (size_t)DD*HH;               // [2,128,2048] bf16
  unsigned short* eprojT = btT;
  unsigned short* aprojT = btT + (size_t)AA*HH;

  // casts
  cast_f32_bf16<<<1024, 256, 0, stream>>>(x,      xb,     (long)TOK*DD/4);
  cast_f32_bf16<<<256,  256, 0, stream>>>(w_gate, wgb,    (long)HH*DD/4);
  cast_f32_bf16<<<256,  256, 0, stream>>>(w_up,   wub,    (long)HH*DD/4);
  cast_f32_bf16<<<256,  256, 0, stream>>>(w_down, wdb,    (long)DD*HH/4);
  cast_f32_bf16<<<256,  256, 0, stream>>>(w_out,  woutb,  (long)DD*HH/4);
  cast_f32_bf16<<<64,   256, 0, stream>>>(w_post, wpostb, (long)AA*HH/4);
  cast_f32_bf16<<<32,   256, 0, stream>>>(w_pre,  wpreb,  (long)AA*DD/4);
  cast_f32_bf16<<<32,   256, 0, stream>>>(w_exp,  wexpb,  (long)EE*AA*AA/4);

  // transpose+cast the fold B operands: [H,A] f32 -> [A,H] bf16
  transpose_cast<<<dim3(AA/32, HH/32), 256, 0, stream>>>(w_eproj, eprojT, HH, AA);
  transpose_cast<<<dim3(AA/32, HH/32), 256, 0, stream>>>(w_aproj, aprojT, HH, AA);

  // folded matrices: z=0: 0.1*w_out@w_eproj -> Wc[:,0:128], z=1: 0.1*w_down@w_aproj -> Wc[:,128:256]
  gemm_bt<6><<<dim3(1, DD/128, 2), 256, 0, stream>>>(
      woutb, (long)(wdb - woutb), HH,
      eprojT, (long)AA*HH, HH,
      Wc, AA, 256, nullptr, 0, 0, HH);

  // gate (silu) then up (*gate), in place into hid — 256² counted-wait path
  gemm256<1, false><<<dim3(HH/256, TOK/256), 512, 0, stream>>>(
      xb, DD, wgb, DD, hid, HH, nullptr, 0, DD, nullptr, 0, nullptr, 0, 0);
  gemm256<2, false><<<dim3(HH/256, TOK/256), 512, 0, stream>>>(
      xb, DD, wub, DD, hid, HH, hid, HH, DD, nullptr, 0, nullptr, 0, 0);

  // pre = x @ w_pre^T, split-K=2 (z = K-half) into two f32 slabs, summed in ln_rows
  gemm_bt<0><<<dim3(1, TOK/128, 2), 256, 0, stream>>>(
      xb, DD/2, DD, wpreb, DD/2, DD, pre, (long)TOK*AA, AA, nullptr, 0, 0, DD/2);
  ln_rows<<<TOK/4, 256, 0, stream>>>(pre, pre + (size_t)TOK*AA, an_g, an_b, ain, preb, ainT);

  // all-expert mix + per-token select/LN -> Fc[:,0:128]
  gemm_bt<3><<<dim3((EE*AA)/128, TOK/128, 1), 256, 0, stream>>>(preb,0,AA, wexpb,0,AA, eall,0,EE*AA, nullptr,0,0, AA);
  expert_select_ln<<<TOK/4, 256, 0, stream>>>(ew, eall, eln_g, eln_b, Fc);

  // adapt_out = LN(hidden @ w_post^T), split-K=2
  gemm_bt<0><<<dim3(1, TOK/128, 2), 256, 0, stream>>>(
      hid, HH/2, HH, wpostb, HH/2, HH, postA, (long)TOK*AA, AA, nullptr, 0, 0, HH/2);
  ln_rows<<<TOK/4, 256, 0, stream>>>(postA, postA + (size_t)TOK*AA, an_g, an_b, aout, nullptr, nullptr);

  // scores: Sc[z] = silu(clip(ain[z] @ aout[z]^T))   (K = A = 128)
  gemm_bt<4><<<dim3(SS/128, SS/128, BB), 256, 0, stream>>>(ain,(long)SS*AA,AA, aout,(long)SS*AA,AA,
                                                           Sc,(long)SS*SS,SS, nullptr,0,0, AA);
  // adapt: Fc[:,128:256] = Sc[z] @ ainT[z]^T
  gemm_bt<3><<<dim3(1, SS/128, BB), 256, 0, stream>>>(Sc,(long)SS*SS,SS, ainT,(long)AA*SS,SS,
                                                      Fc+AA,(long)SS*256,256, nullptr,0,0, SS);
  // out = hid@wdb^T + Fc@Wc'^T  (fp32, Wc' pre-scaled 0.1) — fused-K 256²
  gemm256<0, true><<<dim3(DD/256, TOK/256), 512, 0, stream>>>(
      hid, HH, wdb, HH, (float*)d_out, DD, nullptr, 0, HH, Fc, 256, Wc, 256, 256);
}

// Round 5
// 532.184 us; speedup vs baseline: 2.1239x; 1.0752x over previous
//
#include <hip/hip_runtime.h>

#define TOK 16384
#define DD 1024
#define HH 2048
#define AA 128
#define EE 8
#define SS 2048
#define BB 8

typedef __attribute__((ext_vector_type(8))) short short8;
typedef __attribute__((ext_vector_type(4))) float floatx4;

__device__ __forceinline__ unsigned short f2b(float f) {
  unsigned u = __float_as_uint(f);
  u += 0x7fff + ((u >> 16) & 1);          // RNE
  return (unsigned short)(u >> 16);
}
__device__ __forceinline__ float b2f(unsigned short h) {
  return __uint_as_float(((unsigned)h) << 16);
}

__device__ __forceinline__ void xcd_swizzle(int& bx, int& by) {
  const int nbx = gridDim.x, nby = gridDim.y;
  if ((nby & 7) == 0) {
    const int L = blockIdx.y * nbx + blockIdx.x;
    const int xcd = L & 7, idx = L >> 3;
    bx = idx % nbx;
    by = (xcd * (nby >> 3)) + idx / nbx;
  } else {
    bx = blockIdx.x; by = blockIdx.y;
  }
}

// ================= 256x256 GEMM: counted lgkm + deep staging ring (vmcnt(6)) =================
// 512 thr = 8 waves (2M x 4N), BK=64, LDS 128KiB (2 bufs). Per phase: {ds_reads -> same-phase
// MFMA quadrant via compiler-counted lgkmcnt; 2 global_load_lds; lgkm(0) (free); barrier}.
// Staging ring (2 gloads/phase, m201 discipline): A(t+1).h1 @P0 -> other buf;
// B(t+2).h0 @P2, {B(t+2).h1, A(t+2).h0} @P3 -> current buf. ONE fence per tile at P3:
// vmcnt(6) keeps tile t+2's 6 loads in flight, drains exactly tile t+1's 4 halves
// (issued 3-5 phases earlier -> latency amply covered; never a mid-loop drain-0).
// WAR: A(t+1).h1 overwrites otherbuf.A (last read t-1.P2, >=2 barriers); B(t+2).h0/h1
// overwrite curbuf.B (last read P1); A(t+2).h0 overwrites curbuf.A (last read P2).

__device__ __forceinline__ void gload16(const short* g, short* l) {
  __builtin_amdgcn_global_load_lds((__attribute__((address_space(1))) void*)(void*)g,
                                   (__attribute__((address_space(3))) void*)l, 16, 0, 0);
}

// stage half h (rows h*128..h*128+127) of a 256x64 tile: 2 gloads (i = 2h, 2h+1)
__device__ __forceinline__ void stage_half(const short* src, int ld, short* dst, int wave, int h) {
  gload16(src + (long)(2*h)  *64*ld, dst + (2*h)  *4096 + wave*512);
  gload16(src + (long)(2*h+1)*64*ld, dst + (2*h+1)*4096 + wave*512);
}

#define MFMA_Q(M0, N0)                                                                   \
  __builtin_amdgcn_s_setprio(1);                                                         \
  _Pragma("unroll")                                                                      \
  for (int kk = 0; kk < 2; ++kk)                                                         \
    _Pragma("unroll")                                                                    \
    for (int m = 0; m < 4; ++m)                                                          \
      _Pragma("unroll")                                                                  \
      for (int n = 0; n < 2; ++n)                                                        \
        acc[M0+m][N0+n] = __builtin_amdgcn_mfma_f32_16x16x32_bf16(af[M0+m][kk], bf[N0+n][kk], acc[M0+m][N0+n], 0, 0, 0); \
  __builtin_amdgcn_s_setprio(0);

#define PHASE_END                                                                        \
  asm volatile("s_waitcnt lgkmcnt(0)" ::: "memory");                                     \
  __builtin_amdgcn_s_barrier();                                                          \
  asm volatile("" ::: "memory");

__device__ __forceinline__ void ktile8(const char* cA, const char* cB,   // current bufs
                                       short* oAd, short* cAd, short* cBd, // stage dests
                                       const short* sA1, int lA1,        // A(t+1) base (h1 staged)
                                       const short* sA2, int lA2,        // A(t+2) base (h0 staged)
                                       const short* sB2, int lB2,        // B(t+2) base (h0+h1)
                                       bool st1, bool st2, int wave,
                                       int aOff, int bOff, int slot0, int slot1,
                                       floatx4 (*acc)[4])
{
  short8 af[8][2], bf[4][2];
  // ---- P0: rd af[0-3]+bf[0-1]; stage A(t+1).h1 -> other A; MFMA (m0-3, n0-1) ----
#pragma unroll
  for (int m = 0; m < 4; ++m) {
    af[m][0] = *(const short8*)(cA + aOff + m*2048 + slot0);
    af[m][1] = *(const short8*)(cA + aOff + m*2048 + slot1);
  }
#pragma unroll
  for (int n = 0; n < 2; ++n) {
    bf[n][0] = *(const short8*)(cB + bOff + n*2048 + slot0);
    bf[n][1] = *(const short8*)(cB + bOff + n*2048 + slot1);
  }
  if (st1) stage_half(sA1, lA1, oAd, wave, 1);
  MFMA_Q(0, 0)
  PHASE_END
  // ---- P1: rd bf[2-3]; MFMA (m0-3, n2-3) ----
#pragma unroll
  for (int n = 2; n < 4; ++n) {
    bf[n][0] = *(const short8*)(cB + bOff + n*2048 + slot0);
    bf[n][1] = *(const short8*)(cB + bOff + n*2048 + slot1);
  }
  MFMA_Q(0, 2)
  PHASE_END
  // ---- P2: rd af[4-7]; stage B(t+2).h0 -> cur B; MFMA (m4-7, n0-1) ----
#pragma unroll
  for (int m = 4; m < 8; ++m) {
    af[m][0] = *(const short8*)(cA + aOff + m*2048 + slot0);
    af[m][1] = *(const short8*)(cA + aOff + m*2048 + slot1);
  }
  if (st2) stage_half(sB2, lB2, cBd, wave, 0);
  MFMA_Q(4, 0)
  PHASE_END
  // ---- P3: stage B(t+2).h1 + A(t+2).h0 -> cur bufs; MFMA (m4-7, n2-3); fence ----
  if (st2) {
    stage_half(sB2, lB2, cBd, wave, 1);
    stage_half(sA2, lA2, cAd, wave, 0);
  }
  MFMA_Q(4, 2)
  asm volatile("s_waitcnt lgkmcnt(0)" ::: "memory");
  if (st2) asm volatile("s_waitcnt vmcnt(6)" ::: "memory");  // drains tile t+1; keeps t+2
  else     asm volatile("s_waitcnt vmcnt(0)" ::: "memory");  // tail: drain all
  __builtin_amdgcn_s_barrier();
  asm volatile("" ::: "memory");
}

// C[M,N] = A1[M,K1]@B1[N,K1]^T [+ A2[M,K2]@B2[N,K2]^T if SEG2].  nt must be even, >=4.
// EPI: 0 f32 | 1 silu->bf16 | 2 (*aux)->bf16
template<int EPI, bool SEG2>
__global__ __launch_bounds__(512, 2)
void gemm256(const unsigned short* __restrict__ Ag, int lda,
             const unsigned short* __restrict__ Bg, int ldb,
             void* __restrict__ Cg, int ldc,
             const unsigned short* __restrict__ Xg, int ldx,
             int K1,
             const unsigned short* __restrict__ A2g, int lda2,
             const unsigned short* __restrict__ B2g, int ldb2,
             int K2)
{
  __shared__ __align__(16) short As0[256*64], As1[256*64];
  __shared__ __align__(16) short Bs0[256*64], Bs1[256*64];
  int bx, by; xcd_swizzle(bx, by);
  const int tid = threadIdx.x;
  const int lane = tid & 63, wave = tid >> 6;
  const int q = lane >> 4, l15 = lane & 15;
  const int wm = wave >> 2, wn = wave & 3;

  const int arow = tid >> 3;
  const int kc8  = ((tid & 7) ^ (arow & 7)) * 8;

  const short* a1 = (const short*)Ag + (long)(by*256 + arow)*lda + kc8;
  const short* b1 = (const short*)Bg + (long)(bx*256 + arow)*ldb + kc8;
  const short* a2 = SEG2 ? (const short*)A2g + (long)(by*256 + arow)*lda2 + kc8 : (const short*)0;
  const short* b2 = SEG2 ? (const short*)B2g + (long)(bx*256 + arow)*ldb2 + kc8 : (const short*)0;
  const int nt1 = K1 >> 6, nt = SEG2 ? ((K1 + K2) >> 6) : (K1 >> 6);

  auto tA = [&](int T, const short*& p, int& ld) {
    if (!SEG2 || T < nt1) { p = a1 + T*64; ld = lda; } else { p = a2 + (T - nt1)*64; ld = lda2; }
  };
  auto tB = [&](int T, const short*& p, int& ld) {
    if (!SEG2 || T < nt1) { p = b1 + T*64; ld = ldb; } else { p = b2 + (T - nt1)*64; ld = ldb2; }
  };

  const int aOff  = (wm*128 + l15) * 128;   // bytes
  const int bOff  = (wn*64  + l15) * 128;
  const int l7    = l15 & 7;
  const int slot0 = ((0*4 + q) ^ l7) * 16;
  const int slot1 = ((1*4 + q) ^ l7) * 16;

  floatx4 acc[8][4] = {};

  // prologue (FIFO order matters): t0.A(4), t0.B(4), then t1.B(4), t1.A.h0(2);
  // vmcnt(6) keeps {B1, A1h0} in flight, drains t0 fully.
  stage_half(a1, lda, As0, wave, 0); stage_half(a1, lda, As0, wave, 1);
  stage_half(b1, ldb, Bs0, wave, 0); stage_half(b1, ldb, Bs0, wave, 1);
  {
    const short *pb, *pa; int lb, la;
    tB(1, pb, lb); tA(1, pa, la);
    stage_half(pb, lb, Bs1, wave, 0); stage_half(pb, lb, Bs1, wave, 1);
    stage_half(pa, la, As1, wave, 0);
  }
  asm volatile("s_waitcnt vmcnt(6)" ::: "memory");
  __builtin_amdgcn_s_barrier();
  asm volatile("" ::: "memory");

  for (int t = 0; t < nt; t += 2) {
    const short *pa1, *pa2, *pb2; int la1, la2, lb2;
    // even tile t: bufs (As0,Bs0); other A = As1
    {
      const bool st1 = (t+1) < nt, st2 = (t+2) < nt;
      pa1 = a1; la1 = lda; pa2 = a1; la2 = lda; pb2 = b1; lb2 = ldb;
      if (st1) tA(t+1, pa1, la1);
      if (st2) { tA(t+2, pa2, la2); tB(t+2, pb2, lb2); }
      ktile8((const char*)As0, (const char*)Bs0, As1, As0, Bs0,
             pa1, la1, pa2, la2, pb2, lb2, st1, st2, wave,
             aOff, bOff, slot0, slot1, acc);
    }
    // odd tile t+1: bufs (As1,Bs1); other A = As0
    {
      const bool st1 = (t+2) < nt, st2 = (t+3) < nt;
      pa1 = a1; la1 = lda; pa2 = a1; la2 = lda; pb2 = b1; lb2 = ldb;
      if (st1) tA(t+2, pa1, la1);
      if (st2) { tA(t+3, pa2, la2); tB(t+3, pb2, lb2); }
      ktile8((const char*)As1, (const char*)Bs1, As0, As1, Bs1,
             pa1, la1, pa2, la2, pb2, lb2, st1, st2, wave,
             aOff, bOff, slot0, slot1, acc);
    }
  }

#pragma unroll
  for (int m = 0; m < 8; ++m)
#pragma unroll
    for (int n = 0; n < 4; ++n)
#pragma unroll
      for (int r = 0; r < 4; ++r) {
        const int row = by*256 + wm*128 + m*16 + q*4 + r;
        const int col = bx*256 + wn*64  + n*16 + l15;
        const long ci = (long)row*ldc + col;
        float v = acc[m][n][r];
        if (EPI == 0) {
          ((float*)Cg)[ci] = v;
        } else if (EPI == 1) {
          v = v / (1.f + __expf(-v));
          ((unsigned short*)Cg)[ci] = f2b(v);
        } else if (EPI == 2) {
          float g = b2f(Xg[(long)row*ldx + col]);
          ((unsigned short*)Cg)[ci] = f2b(v * g);
        }
      }
}

// ---- pipelined K-loop (128-tile path for small-N / small-K GEMMs) ----
__device__ __forceinline__ void kloop_pipe(const short* Ap, int lda, const short* Bp, int ldb,
                                           short* As, short* Bs, int K,
                                           int tid, int q, int l15, int l7, int wm, int wn,
                                           floatx4 (*acc)[4])
{
  short8 pa[4], pb[4];
#pragma unroll
  for (int i = 0; i < 4; ++i) {
    pa[i] = *(const short8*)(Ap + (long)i*32*lda);
    pb[i] = *(const short8*)(Bp + (long)i*32*ldb);
  }
  for (int kt = 0; kt < K; kt += 64) {
#pragma unroll
    for (int i = 0; i < 4; ++i) {
      *(short8*)((char*)As + i*4096 + tid*16) = pa[i];
      *(short8*)((char*)Bs + i*4096 + tid*16) = pb[i];
    }
    __syncthreads();
    if (kt + 64 < K) {
#pragma unroll
      for (int i = 0; i < 4; ++i) {
        pa[i] = *(const short8*)(Ap + (long)i*32*lda + kt + 64);
        pb[i] = *(const short8*)(Bp + (long)i*32*ldb + kt + 64);
      }
    }
#pragma unroll
    for (int s = 0; s < 2; ++s) {
      short8 af[4], bf[4];
      const int slotoff = ((s*4 + q) ^ l7) * 16;
#pragma unroll
      for (int i = 0; i < 4; ++i) {
        af[i] = *(const short8*)((const char*)As + (wm*64 + i*16 + l15)*128 + slotoff);
        bf[i] = *(const short8*)((const char*)Bs + (wn*64 + i*16 + l15)*128 + slotoff);
      }
#pragma unroll
      for (int i = 0; i < 4; ++i)
#pragma unroll
        for (int j = 0; j < 4; ++j)
          acc[i][j] = __builtin_amdgcn_mfma_f32_16x16x32_bf16(af[i], bf[j], acc[i][j], 0, 0, 0);
    }
    __syncthreads();
  }
}

// ---------------- fused multi-region f32 -> bf16 cast ----------------
struct CastJobs {
  const float* src[8];
  unsigned short* dst[8];
  long end[8];        // cumulative end, in float4 units
};
__global__ void cast_multi(CastJobs jobs, long total4) {
  long i = (long)blockIdx.x * blockDim.x + threadIdx.x;
  const long stride = (long)gridDim.x * blockDim.x;
  for (; i < total4; i += stride) {
    int r = 0; long base = 0;
#pragma unroll
    for (int k = 0; k < 7; ++k)
      if (i >= jobs.end[k]) { r = k + 1; base = jobs.end[k]; }
    const long o = i - base;
    float4 v = ((const float4*)jobs.src[r])[o];
    ushort4 u;
    u.x = f2b(v.x); u.y = f2b(v.y); u.z = f2b(v.z); u.w = f2b(v.w);
    ((ushort4*)jobs.dst[r])[o] = u;
  }
}

// ---------------- transpose+cast: in[R,C] f32 -> out[C,R] bf16 ----------------
__global__ void transpose_cast(const float* __restrict__ in, unsigned short* __restrict__ out,
                               int R, int C) {
  __shared__ float t[32][33];
  const int lx = threadIdx.x & 31, ly = threadIdx.x >> 5;   // 32x8
  const int r0 = blockIdx.y * 32, c0 = blockIdx.x * 32;
#pragma unroll
  for (int i = 0; i < 32; i += 8)
    t[ly + i][lx] = in[(long)(r0 + ly + i) * C + (c0 + lx)];
  __syncthreads();
#pragma unroll
  for (int i = 0; i < 32; i += 8)
    out[(long)(c0 + ly + i) * R + (r0 + lx)] = f2b(t[lx][ly + i]);
}

// ---------------- MFMA GEMM (128-tile): C[M,N] = A[M,K] @ Bt[N,K]^T ----------------
// EPI: 0 f32 | 1 silu->bf16 | 2 (*aux)->bf16 | 3 bf16 | 4 clip+-5,silu->bf16 | 6 0.1*v->bf16
// SK2: blockIdx.z = batch*2 + khalf; A/B offset by khalf*K; khalf=1 writes to Xg (f32 partial).
template<int EPI, bool SK2 = false>
__global__ __launch_bounds__(256)
void gemm_bt(const unsigned short* __restrict__ Ag, long sAz, int lda,
             const unsigned short* __restrict__ Bg, long sBz, int ldb,
             void* __restrict__ Cg, long sCz, int ldc,
             const unsigned short* __restrict__ Xg, long sXz, int ldx,
             int K)
{
  __shared__ __align__(16) short As[128*64];
  __shared__ __align__(16) short Bs[128*64];
  int bx, by; xcd_swizzle(bx, by);
  const int tid  = threadIdx.x;
  const int lane = tid & 63, wave = tid >> 6;
  const int q = lane >> 4, l15 = lane & 15, l7 = lane & 7;
  const int wm = wave & 1, wn = wave >> 1;

  const int arow = tid >> 3;                       // 0..31
  const int kc8  = ((tid & 7) ^ (arow & 7)) * 8;   // XOR-swizzled k-chunk

  int zb = blockIdx.z, kh = 0;
  if (SK2) { kh = zb & 1; zb >>= 1; }

  const short* Ap = (const short*)Ag + (long)zb*sAz + (long)kh*K + (long)(by*128 + arow)*lda + kc8;
  const short* Bp = (const short*)Bg + (long)zb*sBz + (long)kh*K + (long)(bx*128 + arow)*ldb + kc8;

  floatx4 acc[4][4] = {};
  kloop_pipe(Ap, lda, Bp, ldb, As, Bs, K, tid, q, l15, l7, wm, wn, acc);

  const long cz = (long)zb * sCz;
  const long xz = (long)zb * sXz;
#pragma unroll
  for (int i = 0; i < 4; ++i)
#pragma unroll
    for (int j = 0; j < 4; ++j)
#pragma unroll
      for (int r = 0; r < 4; ++r) {
        const int row = by*128 + wm*64 + i*16 + q*4 + r;
        const int col = bx*128 + wn*64 + j*16 + l15;
        const long ci = cz + (long)row*ldc + col;
        float v = acc[i][j][r];
        if (EPI == 0) {
          if (SK2 && kh) ((float*)(void*)Xg)[ci] = v;
          else           ((float*)Cg)[ci] = v;
        } else if (EPI == 1) {
          v = v / (1.f + __expf(-v));
          ((unsigned short*)Cg)[ci] = f2b(v);
        } else if (EPI == 2) {
          float g = b2f(Xg[xz + (long)row*ldx + col]);
          ((unsigned short*)Cg)[ci] = f2b(v * g);
        } else if (EPI == 3) {
          ((unsigned short*)Cg)[ci] = f2b(v);
        } else if (EPI == 4) {
          v = fminf(fmaxf(v, -5.f), 5.f);
          v = v / (1.f + __expf(-v));
          ((unsigned short*)Cg)[ci] = f2b(v);
        } else if (EPI == 6) {
          ((unsigned short*)Cg)[ci] = f2b(0.1f * v);
        }
      }
}

// ---------------- add two f32 partials -> bf16 into Fc[:,128:256] ----------------
__global__ void addcast_adapt(const float* __restrict__ p0, const float* __restrict__ p1,
                              unsigned short* __restrict__ Fc) {
  const long total = (long)TOK * (AA/4);             // float4 units
  long i = (long)blockIdx.x * blockDim.x + threadIdx.x;
  const long stride = (long)gridDim.x * blockDim.x;
  for (; i < total; i += stride) {
    const long t = i >> 5, a4 = i & 31;              // 32 float4 per row
    float4 a = ((const float4*)p0)[i];
    float4 b = ((const float4*)p1)[i];
    ushort4 u;
    u.x = f2b(a.x + b.x); u.y = f2b(a.y + b.y);
    u.z = f2b(a.z + b.z); u.w = f2b(a.w + b.w);
    *(ushort4*)(Fc + t*256 + AA + a4*4) = u;
  }
}

// ---------------- LayerNorm over A=128 (one wave per row); X2 = split-K partial ----------------
__global__ void ln_rows(const float* __restrict__ X, const float* __restrict__ X2,
                        const float* __restrict__ g,
                        const float* __restrict__ b, unsigned short* __restrict__ lnout,
                        unsigned short* __restrict__ rawout, unsigned short* __restrict__ tout)
{
  const int lane = threadIdx.x & 63, wave = threadIdx.x >> 6;
  const long t = (long)blockIdx.x*4 + wave;
  const float* x  = X  + t*AA;
  const float* x2 = X2 + t*AA;
  float x0 = x[lane]      + x2[lane];
  float x1 = x[lane + 64] + x2[lane + 64];
  float s = x0 + x1, s2 = x0*x0 + x1*x1;
#pragma unroll
  for (int m = 1; m < 64; m <<= 1) {
    s  += __shfl_xor(s, m, 64);
    s2 += __shfl_xor(s2, m, 64);
  }
  float mean = s * (1.f/AA);
  float inv  = rsqrtf(s2*(1.f/AA) - mean*mean + 1e-5f);
  float y0 = (x0 - mean)*inv*g[lane] + b[lane];
  float y1 = (x1 - mean)*inv*g[lane+64] + b[lane+64];
  lnout[t*AA + lane]      = f2b(y0);
  lnout[t*AA + lane + 64] = f2b(y1);
  if (rawout) { rawout[t*AA+lane] = f2b(x0); rawout[t*AA+lane+64] = f2b(x1); }
  if (tout) {
    const long bb = t >> 11, si = t & (SS-1);
    tout[bb*(long)AA*SS + (long)lane*SS + si]      = f2b(y0);
    tout[bb*(long)AA*SS + (long)(lane+64)*SS + si] = f2b(y1);
  }
}

// ---------------- per-token expert select (last positive wins) + LN ----------------
__global__ void expert_select_ln(const float* __restrict__ ew, const unsigned short* __restrict__ eall,
                                 const float* __restrict__ eg, const float* __restrict__ ebias,
                                 unsigned short* __restrict__ Fc)
{
  const int lane = threadIdx.x & 63, wave = threadIdx.x >> 6;
  const long t = (long)blockIdx.x*4 + wave;
  const float* w = ew + t*EE;
  int ie = -1;
#pragma unroll
  for (int i = 0; i < EE; ++i) if (w[i] > 0.f) ie = i;
  unsigned short o0 = 0, o1 = 0;
  if (ie >= 0) {
    float x0 = b2f(eall[t*(EE*AA) + ie*AA + lane]);
    float x1 = b2f(eall[t*(EE*AA) + ie*AA + lane + 64]);
    float s = x0 + x1, s2 = x0*x0 + x1*x1;
#pragma unroll
    for (int m = 1; m < 64; m <<= 1) { s += __shfl_xor(s, m, 64); s2 += __shfl_xor(s2, m, 64); }
    float mean = s * (1.f/AA);
    float inv  = rsqrtf(s2*(1.f/AA) - mean*mean + 1e-5f);
    o0 = f2b((x0-mean)*inv*eg[ie*AA+lane]    + ebias[ie*AA+lane]);
    o1 = f2b((x1-mean)*inv*eg[ie*AA+lane+64] + ebias[ie*AA+lane+64]);
  }
  Fc[t*256 + lane]      = o0;
  Fc[t*256 + lane + 64] = o1;
}

extern "C" void kernel_launch(void* const* d_in, const int* in_sizes, int n_in,
                              void* d_out, int out_size, void* d_ws, size_t ws_size,
                              hipStream_t stream)
{
  const float* x       = (const float*)d_in[0];
  const float* ew      = (const float*)d_in[1];
  const float* w_up    = (const float*)d_in[2];
  const float* w_gate  = (const float*)d_in[3];
  const float* w_down  = (const float*)d_in[4];
  const float* w_pre   = (const float*)d_in[5];
  const float* w_post  = (const float*)d_in[6];
  const float* an_g    = (const float*)d_in[7];
  const float* an_b    = (const float*)d_in[8];
  const float* w_aproj = (const float*)d_in[9];
  const float* w_exp   = (const float*)d_in[10];
  const float* eln_g   = (const float*)d_in[11];
  const float* eln_b   = (const float*)d_in[12];
  const float* w_eproj = (const float*)d_in[13];
  const float* w_out   = (const float*)d_in[14];

  char* ws = (char*)d_ws;
  size_t off = 0;
  auto take = [&](size_t bytes) { char* p = ws + off; off += (bytes + 255) & ~(size_t)255; return p; };

  unsigned short* Sc    = (unsigned short*)take((size_t)BB*SS*SS*2);
  unsigned short* xb    = Sc;
  unsigned short* eall  = (unsigned short*)((char*)Sc + (size_t)TOK*DD*2);
  unsigned short* hid   = (unsigned short*)take((size_t)TOK*HH*2);
  float*          pre   = (float*)take((size_t)TOK*AA*4*2);    // 2 split-K slabs; reused by adapt partials
  float*          postA = (float*)take((size_t)TOK*AA*4*2);    // 2 split-K slabs
  unsigned short* Fc    = (unsigned short*)take((size_t)TOK*256*2);
  unsigned short* ain   = (unsigned short*)take((size_t)TOK*AA*2);
  unsigned short* ainT  = (unsigned short*)take((size_t)TOK*AA*2);
  unsigned short* aout  = (unsigned short*)take((size_t)TOK*AA*2);
  unsigned short* preb  = (unsigned short*)take((size_t)TOK*AA*2);
  unsigned short* wgb   = (unsigned short*)take((size_t)HH*DD*2);
  unsigned short* wub   = (unsigned short*)take((size_t)HH*DD*2);
  unsigned short* wdb   = (unsigned short*)take((size_t)DD*HH*2);
  unsigned short* wpostb= (unsigned short*)take((size_t)AA*HH*2);
  unsigned short* wpreb = (unsigned short*)take((size_t)AA*DD*2);
  unsigned short* wexpb = (unsigned short*)take((size_t)EE*AA*AA*2);
  unsigned short* Wc    = (unsigned short*)take((size_t)DD*256*2);
  (void)ws_size; (void)in_sizes; (void)n_in; (void)out_size;

  unsigned short* woutb  = hid;                               // [1024,2048] bf16
  unsigned short* btT    = hid + (size_t)DD*HH;               // [2,128,2048] bf16
  unsigned short* eprojT = btT;
  unsigned short* aprojT = btT + (size_t)AA*HH;

  // ---- fused casts (x + 7 weight tensors), one launch ----
  {
    CastJobs J;
    const float* s[8]   = { x, w_gate, w_up, w_down, w_out, w_post, w_pre, w_exp };
    unsigned short* d[8]= { xb, wgb,   wub,  wdb,    woutb, wpostb, wpreb, wexpb };
    long n4[8] = { (long)TOK*DD/4, (long)HH*DD/4, (long)HH*DD/4, (long)DD*HH/4,
                   (long)DD*HH/4, (long)AA*HH/4, (long)AA*DD/4, (long)EE*AA*AA/4 };
    long acc4 = 0;
    for (int k = 0; k < 8; ++k) { J.src[k] = s[k]; J.dst[k] = d[k]; acc4 += n4[k]; J.end[k] = acc4; }
    cast_multi<<<2048, 256, 0, stream>>>(J, acc4);
  }

  // transpose+cast the fold B operands: [H,A] f32 -> [A,H] bf16
  transpose_cast<<<dim3(AA/32, HH/32), 256, 0, stream>>>(w_eproj, eprojT, HH, AA);
  transpose_cast<<<dim3(AA/32, HH/32), 256, 0, stream>>>(w_aproj, aprojT, HH, AA);

  // folded matrices: z=0: 0.1*w_out@w_eproj -> Wc[:,0:128], z=1: 0.1*w_down@w_aproj -> Wc[:,128:256]
  gemm_bt<6><<<dim3(1, DD/128, 2), 256, 0, stream>>>(
      woutb, (long)(wdb - woutb), HH,
      eprojT, (long)AA*HH, HH,
      Wc, AA, 256, nullptr, 0, 0, HH);

  // gate (silu) then up (*gate), in place into hid — 256² deep-ring path
  gemm256<1, false><<<dim3(HH/256, TOK/256), 512, 0, stream>>>(
      xb, DD, wgb, DD, hid, HH, nullptr, 0, DD, nullptr, 0, nullptr, 0, 0);
  gemm256<2, false><<<dim3(HH/256, TOK/256), 512, 0, stream>>>(
      xb, DD, wub, DD, hid, HH, hid, HH, DD, nullptr, 0, nullptr, 0, 0);

  // pre = x @ w_pre^T, split-K=2 (z = K-half) into two f32 slabs, summed in ln_rows
  gemm_bt<0><<<dim3(1, TOK/128, 2), 256, 0, stream>>>(
      xb, DD/2, DD, wpreb, DD/2, DD, pre, (long)TOK*AA, AA, nullptr, 0, 0, DD/2);
  ln_rows<<<TOK/4, 256, 0, stream>>>(pre, pre + (size_t)TOK*AA, an_g, an_b, ain, preb, ainT);

  // all-expert mix + per-token select/LN -> Fc[:,0:128]
  gemm_bt<3><<<dim3((EE*AA)/128, TOK/128, 1), 256, 0, stream>>>(preb,0,AA, wexpb,0,AA, eall,0,EE*AA, nullptr,0,0, AA);
  expert_select_ln<<<TOK/4, 256, 0, stream>>>(ew, eall, eln_g, eln_b, Fc);

  // adapt_out = LN(hidden @ w_post^T), split-K=2
  gemm_bt<0><<<dim3(1, TOK/128, 2), 256, 0, stream>>>(
      hid, HH/2, HH, wpostb, HH/2, HH, postA, (long)TOK*AA, AA, nullptr, 0, 0, HH/2);
  ln_rows<<<TOK/4, 256, 0, stream>>>(postA, postA + (size_t)TOK*AA, an_g, an_b, aout, nullptr, nullptr);

  // scores: Sc[z] = silu(clip(ain[z] @ aout[z]^T))   (K = A = 128)
  gemm_bt<4><<<dim3(SS/128, SS/128, BB), 256, 0, stream>>>(ain,(long)SS*AA,AA, aout,(long)SS*AA,AA,
                                                           Sc,(long)SS*SS,SS, nullptr,0,0, AA);
  // adapt = Sc[z] @ ainT[z]^T, split-K=2 (z = batch*2 + khalf), partials into pre slabs
  gemm_bt<0, true><<<dim3(1, SS/128, BB*2), 256, 0, stream>>>(
      Sc, (long)SS*SS, SS, ainT, (long)AA*SS, SS,
      pre, (long)SS*AA, AA, (const unsigned short*)(pre + (size_t)TOK*AA), (long)SS*AA, AA, SS/2);
  addcast_adapt<<<2048, 256, 0, stream>>>(pre, pre + (size_t)TOK*AA, Fc);

  // out = hid@wdb^T + Fc@Wc'^T  (fp32, Wc' pre-scaled 0.1) — fused-K 256²
  gemm256<0, true><<<dim3(DD/256, TOK/256), 512, 0, stream>>>(
      hid, HH, wdb, HH, (float*)d_out, DD, nullptr, 0, HH, Fc, 256, Wc, 256, 256);
}